// Round 1
// baseline (569.928 us; speedup 1.0000x reference)
//
#include <hip/hip_runtime.h>
#include <math.h>

#define BB   2
#define NN   2048
#define HH   8
#define DD   64
#define EE   512
#define DM1  63
#define CC   1.0f
#define EPSV 1e-8f

// ---------------------------------------------------------------------------
// Kernel 1: QKV projection (x @ W^T + b) fused with hyperboloid lift.
// Grid: (64 token-tiles, 8 heads, 3 mats). Block 256.
// Tile: 64 tokens x 63 outputs (one head), K-loop over E in chunks of 64.
// Per-thread 4x4 register tile. Output layout: [B,H,N,64] with d=0 = time.
// ---------------------------------------------------------------------------
__global__ __launch_bounds__(256) void qkv_gemm_lift(
    const float* __restrict__ Xq, const float* __restrict__ Xsrc,
    const float* __restrict__ Wq, const float* __restrict__ Wqb,
    const float* __restrict__ Wk, const float* __restrict__ Wkb,
    const float* __restrict__ Wv, const float* __restrict__ Wvb,
    float* __restrict__ qo, float* __restrict__ ko, float* __restrict__ vo)
{
    const int mt  = blockIdx.x;   // token tile 0..63
    const int h   = blockIdx.y;   // head 0..7
    const int mat = blockIdx.z;   // 0=q 1=k 2=v
    const int t   = threadIdx.x;

    const float* X  = (mat == 0) ? Xq : Xsrc;
    const float* W  = (mat == 0) ? Wq : (mat == 1 ? Wk : Wv);
    const float* Wb = (mat == 0) ? Wqb : (mat == 1 ? Wkb : Wvb);
    float*       O  = (mat == 0) ? qo : (mat == 1 ? ko : vo);

    __shared__ float Xs_[64][68];   // pad 68: row rotation 4 banks
    __shared__ float Ws_[64][68];
    __shared__ float psum[64][17];
    __shared__ float tv[64];

    const int ri = t >> 4;   // 0..15 -> rows 4*ri..4*ri+3
    const int di = t & 15;   // 0..15 -> cols di+16*jj (strided)

    float s[4][4];
#pragma unroll
    for (int i = 0; i < 4; i++)
#pragma unroll
        for (int j = 0; j < 4; j++) s[i][j] = 0.f;

    const int tok0 = mt * 64;

    for (int ek = 0; ek < EE; ek += 64) {
#pragma unroll
        for (int l = 0; l < 4; l++) {
            int g4 = l * 256 + t;          // 0..1023 float4 slots (64 rows x 16)
            int r  = g4 >> 4;
            int e4 = g4 & 15;
            *(float4*)&Xs_[r][e4 * 4] =
                *(const float4*)&X[(size_t)(tok0 + r) * EE + ek + e4 * 4];
            float4 wv4;
            if (r < DM1)
                wv4 = *(const float4*)&W[(size_t)(h * DM1 + r) * EE + ek + e4 * 4];
            else
                wv4 = make_float4(0.f, 0.f, 0.f, 0.f);
            *(float4*)&Ws_[r][e4 * 4] = wv4;
        }
        __syncthreads();
#pragma unroll
        for (int e4 = 0; e4 < 16; e4++) {
            float4 xv[4], wv[4];
#pragma unroll
            for (int i = 0; i < 4; i++)  xv[i] = *(const float4*)&Xs_[ri * 4 + i][e4 * 4];
#pragma unroll
            for (int jj = 0; jj < 4; jj++) wv[jj] = *(const float4*)&Ws_[di + 16 * jj][e4 * 4];
#pragma unroll
            for (int i = 0; i < 4; i++)
#pragma unroll
                for (int jj = 0; jj < 4; jj++)
                    s[i][jj] += xv[i].x * wv[jj].x + xv[i].y * wv[jj].y +
                                xv[i].z * wv[jj].z + xv[i].w * wv[jj].w;
        }
        __syncthreads();
    }

    // bias (j == 63 slot stays 0 and is never written)
#pragma unroll
    for (int jj = 0; jj < 4; jj++) {
        int j = di + 16 * jj;
        float bb = (j < DM1) ? Wb[h * DM1 + j] : 0.f;
#pragma unroll
        for (int i = 0; i < 4; i++) s[i][jj] += bb;
    }

    // per-row sum of squares (lift time component)
#pragma unroll
    for (int i = 0; i < 4; i++) {
        float a = 0.f;
#pragma unroll
        for (int jj = 0; jj < 4; jj++) {
            int j = di + 16 * jj;
            float val = (j < DM1) ? s[i][jj] : 0.f;
            a += val * val;
        }
        psum[ri * 4 + i][di] = a;
    }
    __syncthreads();
    if (t < 64) {
        float ss = 0.f;
#pragma unroll
        for (int d2 = 0; d2 < 16; d2++) ss += psum[t][d2];
        tv[t] = sqrtf(ss + CC);
    }
    __syncthreads();

    // write lifted outputs: O[((b*H+h)*N + n)*64 + d]
#pragma unroll
    for (int i = 0; i < 4; i++) {
        int r   = ri * 4 + i;
        int tok = tok0 + r;
        int b   = tok >> 11;       // /N (2048)
        int n   = tok & 2047;
        size_t base = ((size_t)(b * HH + h) * NN + n) * DD;
#pragma unroll
        for (int jj = 0; jj < 4; jj++) {
            int j = di + 16 * jj;
            if (j < DM1) O[base + 1 + j] = s[i][jj];
        }
    }
    if (t < 64) {
        int tok = tok0 + t;
        int b = tok >> 11;
        int n = tok & 2047;
        O[((size_t)(b * HH + h) * NN + n) * DD] = tv[t];
    }
}

// ---------------------------------------------------------------------------
// Kernel 2: Lorentz attention, per (b,h) with 64-query tiles, fp32.
// Softmax needs no max-subtraction (logits bounded |.|<~2) and constants
// (2C/scale + bias) cancel -> Q staged pre-scaled by +-2/scale.
// Score/P buffer aliases the K tile (phase1 reads K fully before the exp
// write, separated by a barrier) to stay under the 64KB static LDS limit.
// Epilogue: per-head Lorentzian centroid. Output oh: [B,H,N,64].
// ---------------------------------------------------------------------------
__global__ __launch_bounds__(256) void lorentz_attn(
    const float* __restrict__ q, const float* __restrict__ k,
    const float* __restrict__ v, const float* __restrict__ scale_p,
    float* __restrict__ oh)
{
    const int qt = blockIdx.x;   // 0..31 query tile
    const int h  = blockIdx.y;   // 0..7
    const int b  = blockIdx.z;   // 0..1
    const int t  = threadIdx.x;
    const int ri = t >> 4;       // 0..15
    const int di = t & 15;       // 0..15

    __shared__ float qs[64][68];
    __shared__ float ks[64][68];     // aliased as P (exp scores) in phase 2
    __shared__ float vs[64][68];
    __shared__ float psum[64][17];
    __shared__ float rowsum[64];
    __shared__ float ave0[64];
    __shared__ float fct[64];
    float (*Sb)[68] = ks;

    const size_t headbase = (size_t)(b * HH + h) * NN * DD;
    const float  sc = 2.0f / scale_p[0];

    {   // stage Q tile, signed (time comp) and pre-scaled
        const float* qb = q + headbase + (size_t)qt * 64 * DD;
#pragma unroll
        for (int l = 0; l < 4; l++) {
            int g4 = l * 256 + t;
            int r  = g4 >> 4;
            int e4 = g4 & 15;
            float4 x = *(const float4*)&qb[r * DD + e4 * 4];
            if (e4 == 0) x.x = -x.x;
            x.x *= sc; x.y *= sc; x.z *= sc; x.w *= sc;
            *(float4*)&qs[r][e4 * 4] = x;
        }
    }
    if (t < 64) rowsum[t] = 0.f;

    float4 acc[4];
#pragma unroll
    for (int i = 0; i < 4; i++) acc[i] = make_float4(0.f, 0.f, 0.f, 0.f);

    for (int kt = 0; kt < 32; kt++) {
        __syncthreads();   // prev phase2 done (and first-iter qs visible)
        const float* kb = k + headbase + (size_t)kt * 64 * DD;
        const float* vb = v + headbase + (size_t)kt * 64 * DD;
#pragma unroll
        for (int l = 0; l < 4; l++) {
            int g4 = l * 256 + t;
            int r  = g4 >> 4;
            int e4 = g4 & 15;
            *(float4*)&ks[r][e4 * 4] = *(const float4*)&kb[r * DD + e4 * 4];
            *(float4*)&vs[r][e4 * 4] = *(const float4*)&vb[r * DD + e4 * 4];
        }
        __syncthreads();

        // phase 1: S = Qs . K^T   (4 rows x 4 strided cols per thread)
        float s[4][4];
#pragma unroll
        for (int i = 0; i < 4; i++)
#pragma unroll
            for (int j = 0; j < 4; j++) s[i][j] = 0.f;
#pragma unroll
        for (int e4 = 0; e4 < 16; e4++) {
            float4 qv[4], kv[4];
#pragma unroll
            for (int i = 0; i < 4; i++)  qv[i] = *(const float4*)&qs[ri * 4 + i][e4 * 4];
#pragma unroll
            for (int jj = 0; jj < 4; jj++) kv[jj] = *(const float4*)&ks[di + 16 * jj][e4 * 4];
#pragma unroll
            for (int i = 0; i < 4; i++)
#pragma unroll
                for (int jj = 0; jj < 4; jj++)
                    s[i][jj] += qv[i].x * kv[jj].x + qv[i].y * kv[jj].y +
                                qv[i].z * kv[jj].z + qv[i].w * kv[jj].w;
        }
        __syncthreads();   // all K reads done; ks can be overwritten with P

        // exp + stash P into ks alias; per-row partial sums
#pragma unroll
        for (int i = 0; i < 4; i++) {
            float part = 0.f;
#pragma unroll
            for (int jj = 0; jj < 4; jj++) {
                float w = __expf(s[i][jj]);
                Sb[ri * 4 + i][di + 16 * jj] = w;
                part += w;
            }
            psum[ri * 4 + i][di] = part;
        }
        __syncthreads();   // P + psum ready

        if (t < 64) {
            float ss = 0.f;
#pragma unroll
            for (int d2 = 0; d2 < 16; d2++) ss += psum[t][d2];
            rowsum[t] += ss;
        }

        // phase 2: acc += P . V   (4 rows x float4-of-d per thread)
#pragma unroll
        for (int m4 = 0; m4 < 16; m4++) {
            float4 pv[4];
#pragma unroll
            for (int i = 0; i < 4; i++) pv[i] = *(const float4*)&Sb[ri * 4 + i][m4 * 4];
#pragma unroll
            for (int c = 0; c < 4; c++) {
                float4 vv = *(const float4*)&vs[m4 * 4 + c][di * 4];
#pragma unroll
                for (int i = 0; i < 4; i++) {
                    float pc = (c == 0) ? pv[i].x : (c == 1) ? pv[i].y
                             : (c == 2) ? pv[i].z : pv[i].w;
                    acc[i].x += pc * vv.x; acc[i].y += pc * vv.y;
                    acc[i].z += pc * vv.z; acc[i].w += pc * vv.w;
                }
            }
        }
    }
    __syncthreads();   // rowsum final, last phase2 done

    // epilogue: ave = acc/rowsum; per-head Lorentzian centroid
    float4 av[4];
#pragma unroll
    for (int i = 0; i < 4; i++) {
        float inv = 1.0f / rowsum[ri * 4 + i];
        av[i].x = acc[i].x * inv; av[i].y = acc[i].y * inv;
        av[i].z = acc[i].z * inv; av[i].w = acc[i].w * inv;
        psum[ri * 4 + i][di] = av[i].x * av[i].x + av[i].y * av[i].y +
                               av[i].z * av[i].z + av[i].w * av[i].w;
        if (di == 0) ave0[ri * 4 + i] = av[i].x;
    }
    __syncthreads();
    if (t < 64) {
        float ss = 0.f;
#pragma unroll
        for (int d2 = 0; d2 < 16; d2++) ss += psum[t][d2];
        float a0 = ave0[t];
        float inner = ss - 2.0f * a0 * a0;
        fct[t] = sqrtf(CC) / sqrtf(fmaxf(fabsf(inner), EPSV));
    }
    __syncthreads();
    {
        float* ob = oh + headbase + (size_t)qt * 64 * DD;
#pragma unroll
        for (int i = 0; i < 4; i++) {
            int r = ri * 4 + i;
            float f = fct[r];
            float4 o = make_float4(av[i].x * f, av[i].y * f, av[i].z * f, av[i].w * f);
            *(float4*)&ob[r * DD + di * 4] = o;
        }
    }
}

// ---------------------------------------------------------------------------
// Kernel 3: mean over heads + final Lorentzian centroid. One wave per token.
// ---------------------------------------------------------------------------
__global__ __launch_bounds__(256) void finalize_centroid(
    const float* __restrict__ oh, float* __restrict__ out)
{
    const int t    = threadIdx.x;
    const int tok  = blockIdx.x * 4 + (t >> 6);
    const int lane = t & 63;
    const int b = tok >> 11;
    const int n = tok & 2047;

    float m = 0.f;
#pragma unroll
    for (int h = 0; h < HH; h++)
        m += oh[((size_t)(b * HH + h) * NN + n) * DD + lane];
    m *= (1.0f / HH);

    float sq = m * m;
#pragma unroll
    for (int off = 32; off > 0; off >>= 1)
        sq += __shfl_xor(sq, off, 64);
    float m0 = __shfl(m, 0, 64);
    float inner = sq - 2.0f * m0 * m0;
    float f = sqrtf(CC) / sqrtf(fmaxf(fabsf(inner), EPSV));
    out[(size_t)tok * DD + lane] = m * f;
}

extern "C" void kernel_launch(void* const* d_in, const int* in_sizes, int n_in,
                              void* d_out, int out_size, void* d_ws, size_t ws_size,
                              hipStream_t stream)
{
    const float* Xq  = (const float*)d_in[0];
    const float* Xs  = (const float*)d_in[1];
    const float* Wq  = (const float*)d_in[2];
    const float* Wqb = (const float*)d_in[3];
    const float* Wk  = (const float*)d_in[4];
    const float* Wkb = (const float*)d_in[5];
    const float* Wv  = (const float*)d_in[6];
    const float* Wvb = (const float*)d_in[7];
    const float* sc  = (const float*)d_in[8];
    float* out = (float*)d_out;

    float* ws = (float*)d_ws;
    const size_t QKV = (size_t)BB * HH * NN * DD;   // 2,097,152 floats (8 MB)
    float* q  = ws;
    float* k  = q + QKV;
    float* v  = k + QKV;
    float* oh = v + QKV;                            // total 32 MB of d_ws

    qkv_gemm_lift<<<dim3(64, 8, 3), 256, 0, stream>>>(Xq, Xs, Wq, Wqb, Wk, Wkb,
                                                      Wv, Wvb, q, k, v);
    lorentz_attn<<<dim3(32, 8, 2), 256, 0, stream>>>(q, k, v, sc, oh);
    finalize_centroid<<<dim3((BB * NN) / 4), 256, 0, stream>>>(oh, out);
}

// Round 2
// 222.494 us; speedup vs baseline: 2.5615x; 2.5615x over previous
//
#include <hip/hip_runtime.h>
#include <math.h>
#include <stdint.h>

#define BB   2
#define NN   2048
#define HH   8
#define DD   64
#define EE   512
#define DM1  63

typedef _Float16 half8 __attribute__((ext_vector_type(8)));
typedef float    floatx4 __attribute__((ext_vector_type(4)));

// ---------------------------------------------------------------------------
// Kernel 0a: convert Xq / Xsrc fp32 -> f16.  8 elems per thread.
// ---------------------------------------------------------------------------
__global__ __launch_bounds__(256) void convert_x(
    const float* __restrict__ Xq, const float* __restrict__ Xs,
    _Float16* __restrict__ Xq16, _Float16* __restrict__ Xs16)
{
    const int g = blockIdx.x * 256 + threadIdx.x;      // 0..524287
    const int gpi = (BB * NN * EE) / 8;                // 262144 groups per input
    const float* src;  _Float16* dst;  int off;
    if (g < gpi) { src = Xq; dst = Xq16; off = g * 8; }
    else         { src = Xs; dst = Xs16; off = (g - gpi) * 8; }
    float4 a = *(const float4*)(src + off);
    float4 b = *(const float4*)(src + off + 4);
    half8 h;
    h[0] = (_Float16)a.x; h[1] = (_Float16)a.y; h[2] = (_Float16)a.z; h[3] = (_Float16)a.w;
    h[4] = (_Float16)b.x; h[5] = (_Float16)b.y; h[6] = (_Float16)b.z; h[7] = (_Float16)b.w;
    *(half8*)(dst + off) = h;
}

// ---------------------------------------------------------------------------
// Kernel 0b: repack W fp32 [3][504][512] -> f16 [3][8][64][512], row 63 = 0.
// ---------------------------------------------------------------------------
__global__ __launch_bounds__(256) void repack_w(
    const float* __restrict__ Wq, const float* __restrict__ Wk,
    const float* __restrict__ Wv, _Float16* __restrict__ W16)
{
    const int g  = blockIdx.x * 256 + threadIdx.x;     // 0..98303
    const int k8 = g & 63;
    const int j  = (g >> 6) & 63;
    const int h  = (g >> 12) & 7;
    const int mat = g >> 15;
    const float* W = (mat == 0) ? Wq : (mat == 1 ? Wk : Wv);
    half8 out;
    if (j < DM1) {
        const float* p = W + (size_t)(h * DM1 + j) * EE + k8 * 8;
        float4 a = *(const float4*)p;
        float4 b = *(const float4*)(p + 4);
        out[0] = (_Float16)a.x; out[1] = (_Float16)a.y; out[2] = (_Float16)a.z; out[3] = (_Float16)a.w;
        out[4] = (_Float16)b.x; out[5] = (_Float16)b.y; out[6] = (_Float16)b.z; out[7] = (_Float16)b.w;
    } else {
#pragma unroll
        for (int i = 0; i < 8; i++) out[i] = (_Float16)0.f;
    }
    *(half8*)(W16 + (size_t)g * 8) = out;
}

// ---------------------------------------------------------------------------
// Kernel 1: QKV projection via MFMA f16, fused hyperboloid lift.
// Grid (64 token-tiles, 8 heads, 3 mats), block 256 (4 waves x 16 rows).
// Outputs (f16): q [B,H,N,64] pre-scaled by 2/scale & time negated;
//                k [B,H,N,64]; vT [B,H,64,N] (transposed for PV B-frags).
// ---------------------------------------------------------------------------
__global__ __launch_bounds__(256) void qkv_mfma(
    const _Float16* __restrict__ Xq16, const _Float16* __restrict__ Xs16,
    const _Float16* __restrict__ W16,
    const float* __restrict__ Wqb, const float* __restrict__ Wkb,
    const float* __restrict__ Wvb, const float* __restrict__ scale_p,
    _Float16* __restrict__ q16, _Float16* __restrict__ k16,
    _Float16* __restrict__ vT16)
{
    const int mt  = blockIdx.x;
    const int h   = blockIdx.y;
    const int mat = blockIdx.z;
    const int t    = threadIdx.x;
    const int w    = t >> 6;
    const int lane = t & 63;
    const int l15  = lane & 15;
    const int quad = lane >> 4;

    __shared__ alignas(16) _Float16 Xsh[64][72];   // pad: stride 144 B (16B-mult)
    __shared__ alignas(16) _Float16 Wsh[64][72];

    const _Float16* X    = (mat == 0) ? Xq16 : Xs16;
    const _Float16* Wh   = W16 + (size_t)(mat * 8 + h) * 64 * EE;
    const float*    bias = (mat == 0) ? Wqb : (mat == 1 ? Wkb : Wvb);

    const int tok0 = mt * 64;

    floatx4 acc[4];
#pragma unroll
    for (int nt = 0; nt < 4; nt++) acc[nt] = (floatx4){0.f, 0.f, 0.f, 0.f};

    for (int ek = 0; ek < EE; ek += 64) {
        __syncthreads();
#pragma unroll
        for (int ls = 0; ls < 2; ls++) {
            int s = t + 256 * ls, r = s >> 3, c = s & 7;
            *(uint4*)&Xsh[r][c * 8] = *(const uint4*)&X[(size_t)(tok0 + r) * EE + ek + c * 8];
            *(uint4*)&Wsh[r][c * 8] = *(const uint4*)&Wh[(size_t)r * EE + ek + c * 8];
        }
        __syncthreads();
#pragma unroll
        for (int kk = 0; kk < 2; kk++) {
            half8 a = *(const half8*)&Xsh[w * 16 + l15][kk * 32 + quad * 8];
#pragma unroll
            for (int nt = 0; nt < 4; nt++) {
                half8 b = *(const half8*)&Wsh[nt * 16 + l15][kk * 32 + quad * 8];
                acc[nt] = __builtin_amdgcn_mfma_f32_16x16x32_f16(a, b, acc[nt], 0, 0, 0);
            }
        }
    }
    __syncthreads();    // Xsh free -> reuse as output staging

    // epilogue: bias + lift
    float vals[4][4];   // [nt][r]
    float ssq[4] = {0.f, 0.f, 0.f, 0.f};
#pragma unroll
    for (int nt = 0; nt < 4; nt++) {
        int col = nt * 16 + l15;
        float bb = (col < DM1) ? bias[h * DM1 + col] : 0.f;
#pragma unroll
        for (int r = 0; r < 4; r++) {
            float v = acc[nt][r] + bb;
            if (col >= DM1) v = 0.f;
            vals[nt][r] = v;
            ssq[r] += v * v;
        }
    }
    float tim[4];
#pragma unroll
    for (int r = 0; r < 4; r++) {
        float s = ssq[r];
        s += __shfl_xor(s, 1, 64); s += __shfl_xor(s, 2, 64);
        s += __shfl_xor(s, 4, 64); s += __shfl_xor(s, 8, 64);
        tim[r] = sqrtf(s + 1.0f);
    }
    const float sc2  = 2.0f / scale_p[0];
    const float fmul = (mat == 0) ? sc2  : 1.0f;
    const float tmul = (mat == 0) ? -sc2 : 1.0f;
#pragma unroll
    for (int r = 0; r < 4; r++) {
        int row = w * 16 + quad * 4 + r;
#pragma unroll
        for (int nt = 0; nt < 4; nt++) {
            int col = nt * 16 + l15;
            if (col < DM1) Xsh[row][1 + col] = (_Float16)(vals[nt][r] * fmul);
        }
        if (l15 == 0) Xsh[row][0] = (_Float16)(tim[r] * tmul);
    }
    __syncthreads();

    const int b  = tok0 >> 11;
    const int n0 = tok0 & 2047;
    const size_t bh = (size_t)(b * HH + h);
    if (mat < 2) {
        _Float16* O = (mat == 0) ? q16 : k16;
#pragma unroll
        for (int ls = 0; ls < 2; ls++) {
            int s = t + 256 * ls, r = s >> 3, c = s & 7;
            *(uint4*)&O[(bh * NN + n0 + r) * DD + c * 8] = *(const uint4*)&Xsh[r][c * 8];
        }
    } else {
#pragma unroll
        for (int ls = 0; ls < 2; ls++) {
            int s = t + 256 * ls, d = s >> 3, ch = s & 7;
            uint32_t u[4];
#pragma unroll
            for (int i2 = 0; i2 < 4; i2++) {
                _Float16 h0 = Xsh[ch * 8 + i2 * 2][d];
                _Float16 h1 = Xsh[ch * 8 + i2 * 2 + 1][d];
                u[i2] = (uint32_t)(*(uint16_t*)&h0) | ((uint32_t)(*(uint16_t*)&h1) << 16);
            }
            *(uint4*)&vT16[(bh * DD + d) * NN + n0 + ch * 8] =
                make_uint4(u[0], u[1], u[2], u[3]);
        }
    }
}

// ---------------------------------------------------------------------------
// Kernel 2: flash-style Lorentz attention, f16 MFMA.
// Grid (16 q-tiles, 8 heads, 2 batch), block 256 = 4 waves x 32 query rows.
// Register-prefetch double buffer for K/VT tiles. P round-trips through
// wave-local LDS rows (C-layout -> A-layout). No max-subtract (bounded logits;
// constants cancel; 2/scale and Lorentz sign folded into stored q).
// Epilogue: per-head Lorentzian centroid -> oh f16 [B,H,N,64].
// ---------------------------------------------------------------------------
__global__ __launch_bounds__(256) void lorentz_attn_mfma(
    const _Float16* __restrict__ q16, const _Float16* __restrict__ k16,
    const _Float16* __restrict__ vT16, _Float16* __restrict__ oh16)
{
    const int qt = blockIdx.x;
    const int h  = blockIdx.y;
    const int b  = blockIdx.z;
    const int t    = threadIdx.x;
    const int w    = t >> 6;
    const int lane = t & 63;
    const int l15  = lane & 15;
    const int quad = lane >> 4;

    __shared__ alignas(16) _Float16 Qs[128][72];
    __shared__ alignas(16) _Float16 Ks[64][72];
    __shared__ alignas(16) _Float16 VTs[64][72];
    __shared__ alignas(16) _Float16 Ps[128][72];   // wave-local 32-row slabs

    const size_t bh = (size_t)(b * HH + h);
    const _Float16* qbase = q16 + (bh * NN + (size_t)qt * 128) * DD;
    const _Float16* kbase = k16 + bh * NN * DD;
    const _Float16* vbase = vT16 + bh * DD * NN;

    uint4 pk[2], pv[2];
#pragma unroll
    for (int ls = 0; ls < 2; ls++) {          // prefetch tile 0
        int s = t + 256 * ls, r = s >> 3, c = s & 7;
        pk[ls] = *(const uint4*)&kbase[(size_t)r * DD + c * 8];
        pv[ls] = *(const uint4*)&vbase[(size_t)r * NN + c * 8];
    }
#pragma unroll
    for (int ls = 0; ls < 4; ls++) {          // stage Q
        int s = t + 256 * ls, r = s >> 3, c = s & 7;
        *(uint4*)&Qs[r][c * 8] = *(const uint4*)&qbase[(size_t)r * DD + c * 8];
    }
#pragma unroll
    for (int ls = 0; ls < 2; ls++) {          // commit tile 0
        int s = t + 256 * ls, r = s >> 3, c = s & 7;
        *(uint4*)&Ks[r][c * 8]  = pk[ls];
        *(uint4*)&VTs[r][c * 8] = pv[ls];
    }
    __syncthreads();

    half8 qa[2][2];
#pragma unroll
    for (int mt = 0; mt < 2; mt++)
#pragma unroll
        for (int kk = 0; kk < 2; kk++)
            qa[mt][kk] = *(const half8*)&Qs[w * 32 + mt * 16 + l15][kk * 32 + quad * 8];

    floatx4 oacc[2][4];
    float   rs[2][4];
#pragma unroll
    for (int mt = 0; mt < 2; mt++)
#pragma unroll
        for (int nt = 0; nt < 4; nt++) oacc[mt][nt] = (floatx4){0.f, 0.f, 0.f, 0.f};
#pragma unroll
    for (int mt = 0; mt < 2; mt++)
#pragma unroll
        for (int r = 0; r < 4; r++) rs[mt][r] = 0.f;

    for (int kt = 0; kt < 32; kt++) {
        if (kt + 1 < 32) {   // issue prefetch for next tile (lands during compute)
            const _Float16* kb = kbase + (size_t)(kt + 1) * 64 * DD;
#pragma unroll
            for (int ls = 0; ls < 2; ls++) {
                int s = t + 256 * ls, r = s >> 3, c = s & 7;
                pk[ls] = *(const uint4*)&kb[(size_t)r * DD + c * 8];
                pv[ls] = *(const uint4*)&vbase[(size_t)r * NN + (kt + 1) * 64 + c * 8];
            }
        }
        // ---- S = Q . K^T ----
        floatx4 sacc[2][4];
#pragma unroll
        for (int mt = 0; mt < 2; mt++)
#pragma unroll
            for (int nt = 0; nt < 4; nt++) sacc[mt][nt] = (floatx4){0.f, 0.f, 0.f, 0.f};
#pragma unroll
        for (int kk = 0; kk < 2; kk++) {
            half8 kf[4];
#pragma unroll
            for (int nt = 0; nt < 4; nt++)
                kf[nt] = *(const half8*)&Ks[nt * 16 + l15][kk * 32 + quad * 8];
#pragma unroll
            for (int mt = 0; mt < 2; mt++)
#pragma unroll
                for (int nt = 0; nt < 4; nt++)
                    sacc[mt][nt] = __builtin_amdgcn_mfma_f32_16x16x32_f16(
                        qa[mt][kk], kf[nt], sacc[mt][nt], 0, 0, 0);
        }
        // ---- exp + P (wave-local LDS) + row sums ----
#pragma unroll
        for (int mt = 0; mt < 2; mt++) {
            float part[4] = {0.f, 0.f, 0.f, 0.f};
#pragma unroll
            for (int nt = 0; nt < 4; nt++)
#pragma unroll
                for (int r = 0; r < 4; r++) {
                    float wv = __expf(sacc[mt][nt][r]);
                    part[r] += wv;
                    Ps[w * 32 + mt * 16 + quad * 4 + r][nt * 16 + l15] = (_Float16)wv;
                }
#pragma unroll
            for (int r = 0; r < 4; r++) {
                float p = part[r];
                p += __shfl_xor(p, 1, 64); p += __shfl_xor(p, 2, 64);
                p += __shfl_xor(p, 4, 64); p += __shfl_xor(p, 8, 64);
                rs[mt][r] += p;
            }
        }
        // ---- O += P . V  (A-frags from own P rows, B-frags from VT) ----
#pragma unroll
        for (int kk = 0; kk < 2; kk++) {
            half8 vf[4], pa[2];
#pragma unroll
            for (int nt = 0; nt < 4; nt++)
                vf[nt] = *(const half8*)&VTs[nt * 16 + l15][kk * 32 + quad * 8];
#pragma unroll
            for (int mt = 0; mt < 2; mt++)
                pa[mt] = *(const half8*)&Ps[w * 32 + mt * 16 + l15][kk * 32 + quad * 8];
#pragma unroll
            for (int mt = 0; mt < 2; mt++)
#pragma unroll
                for (int nt = 0; nt < 4; nt++)
                    oacc[mt][nt] = __builtin_amdgcn_mfma_f32_16x16x32_f16(
                        pa[mt], vf[nt], oacc[mt][nt], 0, 0, 0);
        }
        __syncthreads();            // K/VT consumed by all waves
        if (kt + 1 < 32) {
#pragma unroll
            for (int ls = 0; ls < 2; ls++) {
                int s = t + 256 * ls, r = s >> 3, c = s & 7;
                *(uint4*)&Ks[r][c * 8]  = pk[ls];
                *(uint4*)&VTs[r][c * 8] = pv[ls];
            }
            __syncthreads();        // next tile staged
        }
    }

    // ---- epilogue: normalize + per-head Lorentzian centroid ----
#pragma unroll
    for (int mt = 0; mt < 2; mt++) {
        float av[4][4];   // [nt][r]
        float ssq[4] = {0.f, 0.f, 0.f, 0.f};
#pragma unroll
        for (int r = 0; r < 4; r++) {
            float inv = 1.0f / rs[mt][r];
#pragma unroll
            for (int nt = 0; nt < 4; nt++) {
                float a = oacc[mt][nt][r] * inv;
                av[nt][r] = a;
                ssq[r] += a * a;
            }
        }
#pragma unroll
        for (int r = 0; r < 4; r++) {
            float s = ssq[r];
            s += __shfl_xor(s, 1, 64); s += __shfl_xor(s, 2, 64);
            s += __shfl_xor(s, 4, 64); s += __shfl_xor(s, 8, 64);
            float a0 = __shfl(av[0][r], quad * 16, 64);   // col 0 (time) of this row
            float inner = s - 2.0f * a0 * a0;
            float f = rsqrtf(fmaxf(fabsf(inner), 1e-8f));
#pragma unroll
            for (int nt = 0; nt < 4; nt++)
                Ps[w * 32 + mt * 16 + quad * 4 + r][nt * 16 + l15] =
                    (_Float16)(av[nt][r] * f);
        }
    }
    __syncthreads();
    _Float16* ob = oh16 + (bh * NN + (size_t)qt * 128) * DD;
#pragma unroll
    for (int ls = 0; ls < 4; ls++) {
        int s = t + 256 * ls, r = s >> 3, c = s & 7;
        *(uint4*)&ob[(size_t)r * DD + c * 8] = *(const uint4*)&Ps[r][c * 8];
    }
}

// ---------------------------------------------------------------------------
// Kernel 3: mean over heads + final Lorentzian centroid. One wave per token.
// ---------------------------------------------------------------------------
__global__ __launch_bounds__(256) void finalize_f16(
    const _Float16* __restrict__ oh16, float* __restrict__ out)
{
    const int t    = threadIdx.x;
    const int tok  = blockIdx.x * 4 + (t >> 6);
    const int lane = t & 63;
    const int b = tok >> 11;
    const int n = tok & 2047;

    float m = 0.f;
#pragma unroll
    for (int h = 0; h < HH; h++)
        m += (float)oh16[((size_t)(b * HH + h) * NN + n) * DD + lane];
    m *= 0.125f;

    float sq = m * m;
#pragma unroll
    for (int off = 32; off > 0; off >>= 1)
        sq += __shfl_xor(sq, off, 64);
    float m0 = __shfl(m, 0, 64);
    float inner = sq - 2.0f * m0 * m0;
    float f = rsqrtf(fmaxf(fabsf(inner), 1e-8f));
    out[(size_t)tok * DD + lane] = m * f;
}

extern "C" void kernel_launch(void* const* d_in, const int* in_sizes, int n_in,
                              void* d_out, int out_size, void* d_ws, size_t ws_size,
                              hipStream_t stream)
{
    const float* Xq  = (const float*)d_in[0];
    const float* Xs  = (const float*)d_in[1];
    const float* Wq  = (const float*)d_in[2];
    const float* Wqb = (const float*)d_in[3];
    const float* Wk  = (const float*)d_in[4];
    const float* Wkb = (const float*)d_in[5];
    const float* Wv  = (const float*)d_in[6];
    const float* Wvb = (const float*)d_in[7];
    const float* sc  = (const float*)d_in[8];
    float* out = (float*)d_out;

    _Float16* p = (_Float16*)d_ws;
    const size_t XSZ = (size_t)BB * NN * EE;       // 2,097,152
    const size_t WSZ = (size_t)3 * 8 * 64 * EE;    //   786,432
    const size_t QSZ = (size_t)BB * HH * NN * DD;  // 2,097,152
    _Float16* Xq16 = p;               p += XSZ;
    _Float16* Xs16 = p;               p += XSZ;
    _Float16* W16  = p;               p += WSZ;
    _Float16* q16  = p;               p += QSZ;
    _Float16* k16  = p;               p += QSZ;
    _Float16* vT16 = p;               p += QSZ;
    _Float16* oh16 = p;               p += QSZ;    // total ~26.7 MB

    convert_x<<<2048, 256, 0, stream>>>(Xq, Xs, Xq16, Xs16);
    repack_w<<<384, 256, 0, stream>>>(Wq, Wk, Wv, W16);
    qkv_mfma<<<dim3(64, 8, 3), 256, 0, stream>>>(Xq16, Xs16, W16, Wqb, Wkb, Wvb,
                                                 sc, q16, k16, vT16);
    lorentz_attn_mfma<<<dim3(16, 8, 2), 256, 0, stream>>>(q16, k16, vT16, oh16);
    finalize_f16<<<(BB * NN) / 4, 256, 0, stream>>>(oh16, out);
}

// Round 4
// 193.900 us; speedup vs baseline: 2.9393x; 1.1475x over previous
//
#include <hip/hip_runtime.h>
#include <math.h>
#include <stdint.h>

#define BB   2
#define NN   2048
#define HH   8
#define DD   64
#define EE   512
#define DM1  63

typedef _Float16 half8  __attribute__((ext_vector_type(8)));
typedef __fp16   fp16x2 __attribute__((ext_vector_type(2)));
typedef float    floatx4 __attribute__((ext_vector_type(4)));

__device__ __forceinline__ uint32_t pkh2(float a, float b) {
    union { fp16x2 h; uint32_t u; } uu;
    uu.h = __builtin_amdgcn_cvt_pkrtz(a, b);
    return uu.u;
}

// ---------------------------------------------------------------------------
// Kernel 0: fused convert (X fp32->f16) + repack (W -> [3][8][64][512] f16,
// row 63 of each head zeroed).
// ---------------------------------------------------------------------------
__global__ __launch_bounds__(256) void prep(
    const float* __restrict__ Xq, const float* __restrict__ Xs,
    const float* __restrict__ Wq, const float* __restrict__ Wk,
    const float* __restrict__ Wv,
    _Float16* __restrict__ Xq16, _Float16* __restrict__ Xs16,
    _Float16* __restrict__ W16)
{
    const int blk = blockIdx.x;
    if (blk < 2048) {
        const int g = blk * 256 + threadIdx.x;          // 0..524287
        const int gpi = (BB * NN * EE) / 8;             // 262144
        const float* src;  _Float16* dst;  int off;
        if (g < gpi) { src = Xq; dst = Xq16; off = g * 8; }
        else         { src = Xs; dst = Xs16; off = (g - gpi) * 8; }
        float4 a = *(const float4*)(src + off);
        float4 b = *(const float4*)(src + off + 4);
        half8 h;
        h[0]=(_Float16)a.x; h[1]=(_Float16)a.y; h[2]=(_Float16)a.z; h[3]=(_Float16)a.w;
        h[4]=(_Float16)b.x; h[5]=(_Float16)b.y; h[6]=(_Float16)b.z; h[7]=(_Float16)b.w;
        *(half8*)(dst + off) = h;
    } else {
        const int g  = (blk - 2048) * 256 + threadIdx.x;  // 0..98303
        const int k8 = g & 63;
        const int j  = (g >> 6) & 63;
        const int h  = (g >> 12) & 7;
        const int mat = g >> 15;
        const float* W = (mat == 0) ? Wq : (mat == 1 ? Wk : Wv);
        half8 out;
        if (j < DM1) {
            const float* p = W + (size_t)(h * DM1 + j) * EE + k8 * 8;
            float4 a = *(const float4*)p;
            float4 b = *(const float4*)(p + 4);
            out[0]=(_Float16)a.x; out[1]=(_Float16)a.y; out[2]=(_Float16)a.z; out[3]=(_Float16)a.w;
            out[4]=(_Float16)b.x; out[5]=(_Float16)b.y; out[6]=(_Float16)b.z; out[7]=(_Float16)b.w;
        } else {
#pragma unroll
            for (int i = 0; i < 8; i++) out[i] = (_Float16)0.f;
        }
        *(half8*)(W16 + (size_t)g * 8) = out;
    }
}

// ---------------------------------------------------------------------------
// Kernel 1: QKV MFMA projection + lift. Grid (64 tok-tiles, 4 head-pairs, 3).
// Block 256 = 4 waves; tile 64 tok x 128 cols (2 heads). Register prefetch.
// Outputs: q [B,H,N,64] (prescaled 2/scale, time negated), k [B,H,N,64],
//          vT [B,H,64,N].
// ---------------------------------------------------------------------------
__global__ __launch_bounds__(256, 2) void qkv_mfma(
    const _Float16* __restrict__ Xq16, const _Float16* __restrict__ Xs16,
    const _Float16* __restrict__ W16,
    const float* __restrict__ Wqb, const float* __restrict__ Wkb,
    const float* __restrict__ Wvb, const float* __restrict__ scale_p,
    _Float16* __restrict__ q16, _Float16* __restrict__ k16,
    _Float16* __restrict__ vT16)
{
    const int mtb = blockIdx.x;   // token tile
    const int hp  = blockIdx.y;   // head pair 0..3
    const int mat = blockIdx.z;
    const int t    = threadIdx.x;
    const int w    = t >> 6;
    const int lane = t & 63;
    const int l15  = lane & 15;
    const int quad = lane >> 4;

    __shared__ alignas(16) char smem[27648];
    __shared__ float psum[64][4];
    _Float16 (*Xsh)[72]  = (_Float16(*)[72])smem;            //  9216 B
    _Float16 (*Wsh)[72]  = (_Float16(*)[72])(smem + 9216);   // 18432 B
    _Float16 (*Osh)[136] = (_Float16(*)[136])(smem + 9216);  // alias (17408 B)
    _Float16 (*OshT)[72] = (_Float16(*)[72])(smem + 9216);   // alias (18432 B)

    const _Float16* X     = (mat == 0) ? Xq16 : Xs16;
    const _Float16* Wbase = W16 + (size_t)((mat * 8 + hp * 2) * 64) * EE;
    const int tok0 = mtb * 64;

    floatx4 acc[4][2];
#pragma unroll
    for (int mt = 0; mt < 4; mt++)
#pragma unroll
        for (int nt = 0; nt < 2; nt++) acc[mt][nt] = (floatx4){0.f,0.f,0.f,0.f};

    uint4 px[2], pw[4];
#pragma unroll
    for (int ls = 0; ls < 2; ls++) {
        int s = t + 256 * ls, r = s >> 3, c = s & 7;
        px[ls] = *(const uint4*)&X[(size_t)(tok0 + r) * EE + c * 8];
    }
#pragma unroll
    for (int ls = 0; ls < 4; ls++) {
        int s = t + 256 * ls, r = s >> 3, c = s & 7;
        pw[ls] = *(const uint4*)&Wbase[(size_t)r * EE + c * 8];
    }

    for (int it = 0; it < 8; it++) {
        __syncthreads();
#pragma unroll
        for (int ls = 0; ls < 2; ls++) {
            int s = t + 256 * ls, r = s >> 3, c = s & 7;
            *(uint4*)&Xsh[r][c * 8] = px[ls];
        }
#pragma unroll
        for (int ls = 0; ls < 4; ls++) {
            int s = t + 256 * ls, r = s >> 3, c = s & 7;
            *(uint4*)&Wsh[r][c * 8] = pw[ls];
        }
        __syncthreads();
        if (it + 1 < 8) {
            int ek = (it + 1) * 64;
#pragma unroll
            for (int ls = 0; ls < 2; ls++) {
                int s = t + 256 * ls, r = s >> 3, c = s & 7;
                px[ls] = *(const uint4*)&X[(size_t)(tok0 + r) * EE + ek + c * 8];
            }
#pragma unroll
            for (int ls = 0; ls < 4; ls++) {
                int s = t + 256 * ls, r = s >> 3, c = s & 7;
                pw[ls] = *(const uint4*)&Wbase[(size_t)r * EE + ek + c * 8];
            }
        }
#pragma unroll
        for (int kk = 0; kk < 2; kk++) {
            half8 a[4];
#pragma unroll
            for (int mt = 0; mt < 4; mt++)
                a[mt] = *(const half8*)&Xsh[mt * 16 + l15][kk * 32 + quad * 8];
#pragma unroll
            for (int nt = 0; nt < 2; nt++) {
                half8 bfr = *(const half8*)&Wsh[w * 32 + nt * 16 + l15][kk * 32 + quad * 8];
#pragma unroll
                for (int mt = 0; mt < 4; mt++)
                    acc[mt][nt] = __builtin_amdgcn_mfma_f32_16x16x32_f16(
                        a[mt], bfr, acc[mt][nt], 0, 0, 0);
            }
        }
    }
    __syncthreads();   // Wsh dead -> Osh/OshT alias safe

    const float* bias = (mat == 0) ? Wqb : (mat == 1 ? Wkb : Wvb);
    const float st   = 2.0f / scale_p[0];
    const float fmul = (mat == 0) ? st : 1.0f;

    float vals[4][2][4];
    float sqp[4][4];
#pragma unroll
    for (int mt = 0; mt < 4; mt++)
#pragma unroll
        for (int r = 0; r < 4; r++) sqp[mt][r] = 0.f;

#pragma unroll
    for (int mt = 0; mt < 4; mt++)
#pragma unroll
        for (int nt = 0; nt < 2; nt++) {
            int col = w * 32 + nt * 16 + l15;
            int head = col >> 6, j = col & 63;
            float bb = (j < DM1) ? bias[(hp * 2 + head) * DM1 + j] : 0.f;
#pragma unroll
            for (int r = 0; r < 4; r++) {
                float vv = acc[mt][nt][r] + bb;
                if (j >= DM1) vv = 0.f;
                vals[mt][nt][r] = vv;
                sqp[mt][r] += vv * vv;
            }
        }
#pragma unroll
    for (int mt = 0; mt < 4; mt++)
#pragma unroll
        for (int r = 0; r < 4; r++) {
            float s = sqp[mt][r];
            s += __shfl_xor(s, 1, 64); s += __shfl_xor(s, 2, 64);
            s += __shfl_xor(s, 4, 64); s += __shfl_xor(s, 8, 64);
            if (l15 == 0) psum[mt * 16 + quad * 4 + r][w] = s;
        }

    if (mat < 2) {
#pragma unroll
        for (int mt = 0; mt < 4; mt++)
#pragma unroll
            for (int nt = 0; nt < 2; nt++) {
                int col = w * 32 + nt * 16 + l15;
                int head = col >> 6, j = col & 63;
                if (j < DM1) {
                    int dc = head * 64 + 1 + j;
#pragma unroll
                    for (int r = 0; r < 4; r++)
                        Osh[mt * 16 + quad * 4 + r][dc] = (_Float16)(vals[mt][nt][r] * fmul);
                }
            }
    } else {
#pragma unroll
        for (int mt = 0; mt < 4; mt++)
#pragma unroll
            for (int nt = 0; nt < 2; nt++) {
                int col = w * 32 + nt * 16 + l15;
                uint2 pu;
                pu.x = pkh2(vals[mt][nt][0], vals[mt][nt][1]);
                pu.y = pkh2(vals[mt][nt][2], vals[mt][nt][3]);
                *(uint2*)&OshT[col][mt * 16 + quad * 4] = pu;
            }
    }
    __syncthreads();
    if (t < 64) {
        float tsA = sqrtf(psum[t][0] + psum[t][1] + 1.0f);
        float tsB = sqrtf(psum[t][2] + psum[t][3] + 1.0f);
        if (mat < 2) {
            float tm = (mat == 0) ? -st : 1.0f;
            Osh[t][0]  = (_Float16)(tsA * tm);
            Osh[t][64] = (_Float16)(tsB * tm);
        } else {
            OshT[63][t]  = (_Float16)tsA;
            OshT[127][t] = (_Float16)tsB;
        }
    }
    __syncthreads();

    const int bI = tok0 >> 11, n0 = tok0 & 2047;
    if (mat < 2) {
        _Float16* O = (mat == 0) ? q16 : k16;
#pragma unroll
        for (int ls = 0; ls < 4; ls++) {
            int s = t + 256 * ls, r = s >> 4, c = s & 15, head = c >> 3;
            size_t bh = (size_t)(bI * HH + hp * 2 + head);
            *(uint4*)&O[(bh * NN + n0 + r) * DD + (c & 7) * 8] = *(const uint4*)&Osh[r][c * 8];
        }
    } else {
#pragma unroll
        for (int ls = 0; ls < 4; ls++) {
            int s = t + 256 * ls, df = s >> 3, c = s & 7;
            int head = df >> 6, d = df & 63;
            int rr = head * 64 + ((d + 63) & 63);   // d=0 -> row 63 (time slot)
            size_t bh = (size_t)(bI * HH + hp * 2 + head);
            *(uint4*)&vT16[(bh * DD + d) * NN + n0 + c * 8] = *(const uint4*)&OshT[rr][c * 8];
        }
    }
}

// ---------------------------------------------------------------------------
// Kernel 2: Lorentz flash attention, f16 MFMA, in-block split-K.
// Grid (32 qt, 8 h, 2 b), block 256 = 2 wave-pairs. Pair p handles K-tiles
// p*16..p*16+15 with its own LDS K/VT/P buffers; partials merged in LDS.
// S^T = K·Q^T (so P packs as b64 and reads back as A-frag b128). Rowsum via
// ones-row (VT row 64 = 1) as PV's 5th n-tile. Per-head centroid in epilogue.
// ---------------------------------------------------------------------------
__global__ __launch_bounds__(256, 2) void lorentz_attn_v3(
    const _Float16* __restrict__ q16, const _Float16* __restrict__ k16,
    const _Float16* __restrict__ vT16, _Float16* __restrict__ oh16)
{
    const int qt = blockIdx.x;    // 64 q-rows per block
    const int h  = blockIdx.y;
    const int b  = blockIdx.z;
    const int t    = threadIdx.x;
    const int w    = t >> 6;      // 0..3
    const int p    = w >> 1;      // pair (K-split half)
    const int wq   = w & 1;       // q-row half within pair
    const int tp   = t & 127;     // thread id within pair
    const int lane = t & 63;
    const int l15  = lane & 15;
    const int quad = lane >> 4;

    __shared__ alignas(16) char smem[59904];
    _Float16 (*Ks)[72]  = (_Float16(*)[72])(smem + p * 29952);          // 64x72
    _Float16 (*VTs)[72] = (_Float16(*)[72])(smem + p * 29952 + 9216);   // 80x72
    _Float16 (*Ps)[72]  = (_Float16(*)[72])(smem + p * 29952 + 20736);  // 64x72
    float (*Mrg)[84]    = (float(*)[84])(smem + 29952);                 // 64x84 f32
    _Float16 (*Ps0)[72] = (_Float16(*)[72])(smem + 20736);

    const size_t bh = (size_t)(b * HH + h);
    const _Float16* kbase = k16 + bh * NN * DD;
    const _Float16* vbase = vT16 + bh * DD * NN;
    const int kt0 = p * 16;

    // VTs rows 64..79: row 64 = ones (rowsum trick), 65..79 = zeros
    {
        uint32_t* vrow = (uint32_t*)&VTs[64][0];
        for (int i = tp; i < 16 * 36; i += 128)
            vrow[i] = (i < 36) ? 0x3C003C00u : 0u;
    }

    // Q B-fragments direct from global (q pre-scaled, time pre-negated)
    half8 qb[2][2];
#pragma unroll
    for (int mt = 0; mt < 2; mt++)
#pragma unroll
        for (int kk = 0; kk < 2; kk++)
            qb[mt][kk] = *(const half8*)&q16[
                (bh * NN + (size_t)qt * 64 + wq * 32 + mt * 16 + l15) * DD + kk * 32 + quad * 8];

    // prefetch + commit first tile
    uint4 pk[4], pv[4];
#pragma unroll
    for (int ls = 0; ls < 4; ls++) {
        int s = tp + 128 * ls, r = s >> 3, c = s & 7;
        pk[ls] = *(const uint4*)&kbase[((size_t)kt0 * 64 + r) * DD + c * 8];
        pv[ls] = *(const uint4*)&vbase[(size_t)r * NN + kt0 * 64 + c * 8];
    }
#pragma unroll
    for (int ls = 0; ls < 4; ls++) {
        int s = tp + 128 * ls, r = s >> 3, c = s & 7;
        *(uint4*)&Ks[r][c * 8]  = pk[ls];
        *(uint4*)&VTs[r][c * 8] = pv[ls];
    }
    __syncthreads();

    floatx4 oacc[2][5];
#pragma unroll
    for (int mt = 0; mt < 2; mt++)
#pragma unroll
        for (int nt = 0; nt < 5; nt++) oacc[mt][nt] = (floatx4){0.f,0.f,0.f,0.f};

    for (int i = 0; i < 16; i++) {
        const int kt = kt0 + i;
        if (i + 1 < 16) {
            const _Float16* kb = kbase + (size_t)(kt + 1) * 64 * DD;
#pragma unroll
            for (int ls = 0; ls < 4; ls++) {
                int s = tp + 128 * ls, r = s >> 3, c = s & 7;
                pk[ls] = *(const uint4*)&kb[(size_t)r * DD + c * 8];
                pv[ls] = *(const uint4*)&vbase[(size_t)r * NN + (kt + 1) * 64 + c * 8];
            }
        }
        // ---- S^T = K . Q^T  (rows=kv, cols=qrow) ----
        floatx4 sacc[4][2];
#pragma unroll
        for (int nt = 0; nt < 4; nt++)
#pragma unroll
            for (int mt = 0; mt < 2; mt++) sacc[nt][mt] = (floatx4){0.f,0.f,0.f,0.f};
#pragma unroll
        for (int kk = 0; kk < 2; kk++) {
#pragma unroll
            for (int nt = 0; nt < 4; nt++) {
                half8 kf = *(const half8*)&Ks[nt * 16 + l15][kk * 32 + quad * 8];
#pragma unroll
                for (int mt = 0; mt < 2; mt++)
                    sacc[nt][mt] = __builtin_amdgcn_mfma_f32_16x16x32_f16(
                        kf, qb[mt][kk], sacc[nt][mt], 0, 0, 0);
            }
        }
        // ---- exp -> pack -> Ps[qrow][kv] (b64, wave-local) ----
#pragma unroll
        for (int nt = 0; nt < 4; nt++)
#pragma unroll
            for (int mt = 0; mt < 2; mt++) {
                uint2 pu;
                pu.x = pkh2(__expf(sacc[nt][mt][0]), __expf(sacc[nt][mt][1]));
                pu.y = pkh2(__expf(sacc[nt][mt][2]), __expf(sacc[nt][mt][3]));
                *(uint2*)&Ps[wq * 32 + mt * 16 + l15][nt * 16 + quad * 4] = pu;
            }
        // ---- O += P . [V ; 1] ----
#pragma unroll
        for (int kk = 0; kk < 2; kk++) {
            half8 pa[2];
#pragma unroll
            for (int mt = 0; mt < 2; mt++)
                pa[mt] = *(const half8*)&Ps[wq * 32 + mt * 16 + l15][kk * 32 + quad * 8];
#pragma unroll
            for (int nt = 0; nt < 5; nt++) {
                half8 vf = *(const half8*)&VTs[nt * 16 + l15][kk * 32 + quad * 8];
#pragma unroll
                for (int mt = 0; mt < 2; mt++)
                    oacc[mt][nt] = __builtin_amdgcn_mfma_f32_16x16x32_f16(
                        pa[mt], vf, oacc[mt][nt], 0, 0, 0);
            }
        }
        __syncthreads();
        if (i + 1 < 16) {
#pragma unroll
            for (int ls = 0; ls < 4; ls++) {
                int s = tp + 128 * ls, r = s >> 3, c = s & 7;
                *(uint4*)&Ks[r][c * 8]  = pk[ls];
                *(uint4*)&VTs[r][c * 8] = pv[ls];
            }
            __syncthreads();
        }
    }

    // ---- merge pair-1 partials into pair-0 ----
    if (p == 1) {
#pragma unroll
        for (int mt = 0; mt < 2; mt++)
#pragma unroll
            for (int nt = 0; nt < 5; nt++)
#pragma unroll
                for (int r = 0; r < 4; r++)
                    Mrg[wq * 32 + mt * 16 + quad * 4 + r][nt * 16 + l15] = oacc[mt][nt][r];
    }
    __syncthreads();
    if (p == 0) {
#pragma unroll
        for (int mt = 0; mt < 2; mt++)
#pragma unroll
            for (int nt = 0; nt < 5; nt++)
#pragma unroll
                for (int r = 0; r < 4; r++)
                    oacc[mt][nt][r] += Mrg[wq * 32 + mt * 16 + quad * 4 + r][nt * 16 + l15];

        // ---- normalize + per-head Lorentzian centroid ----
#pragma unroll
        for (int mt = 0; mt < 2; mt++)
#pragma unroll
            for (int r = 0; r < 4; r++) {
                float rsum = __shfl(oacc[mt][4][r], quad * 16, 64);  // ones column
                float inv = 1.0f / rsum;
                float a[4], ssq = 0.f;
#pragma unroll
                for (int nt = 0; nt < 4; nt++) {
                    a[nt] = oacc[mt][nt][r] * inv;
                    ssq += a[nt] * a[nt];
                }
                ssq += __shfl_xor(ssq, 1, 64); ssq += __shfl_xor(ssq, 2, 64);
                ssq += __shfl_xor(ssq, 4, 64); ssq += __shfl_xor(ssq, 8, 64);
                float a0 = __shfl(a[0], quad * 16, 64);              // time component
                float inner = ssq - 2.0f * a0 * a0;
                float f = rsqrtf(fmaxf(fabsf(inner), 1e-8f));
#pragma unroll
                for (int nt = 0; nt < 4; nt++)
                    Ps0[wq * 32 + mt * 16 + quad * 4 + r][nt * 16 + l15] =
                        (_Float16)(a[nt] * f);
            }
    }
    __syncthreads();
    _Float16* ob = oh16 + (bh * NN + (size_t)qt * 64) * DD;
#pragma unroll
    for (int ls = 0; ls < 2; ls++) {
        int s = t + 256 * ls, r = s >> 3, c = s & 7;
        *(uint4*)&ob[(size_t)r * DD + c * 8] = *(const uint4*)&Ps0[r][c * 8];
    }
}

// ---------------------------------------------------------------------------
// Kernel 3: mean over heads + final Lorentzian centroid. One wave per token.
// ---------------------------------------------------------------------------
__global__ __launch_bounds__(256) void finalize_f16(
    const _Float16* __restrict__ oh16, float* __restrict__ out)
{
    const int t    = threadIdx.x;
    const int tok  = blockIdx.x * 4 + (t >> 6);
    const int lane = t & 63;
    const int b = tok >> 11;
    const int n = tok & 2047;

    float m = 0.f;
#pragma unroll
    for (int h = 0; h < HH; h++)
        m += (float)oh16[((size_t)(b * HH + h) * NN + n) * DD + lane];
    m *= 0.125f;

    float sq = m * m;
#pragma unroll
    for (int off = 32; off > 0; off >>= 1)
        sq += __shfl_xor(sq, off, 64);
    float m0 = __shfl(m, 0, 64);
    float inner = sq - 2.0f * m0 * m0;
    float f = rsqrtf(fmaxf(fabsf(inner), 1e-8f));
    out[(size_t)tok * DD + lane] = m * f;
}

extern "C" void kernel_launch(void* const* d_in, const int* in_sizes, int n_in,
                              void* d_out, int out_size, void* d_ws, size_t ws_size,
                              hipStream_t stream)
{
    const float* Xq  = (const float*)d_in[0];
    const float* Xs  = (const float*)d_in[1];
    const float* Wq  = (const float*)d_in[2];
    const float* Wqb = (const float*)d_in[3];
    const float* Wk  = (const float*)d_in[4];
    const float* Wkb = (const float*)d_in[5];
    const float* Wv  = (const float*)d_in[6];
    const float* Wvb = (const float*)d_in[7];
    const float* sc  = (const float*)d_in[8];
    float* out = (float*)d_out;

    _Float16* p = (_Float16*)d_ws;
    const size_t XSZ = (size_t)BB * NN * EE;
    const size_t WSZ = (size_t)3 * 8 * 64 * EE;
    const size_t QSZ = (size_t)BB * HH * NN * DD;
    _Float16* Xq16 = p;  p += XSZ;
    _Float16* Xs16 = p;  p += XSZ;
    _Float16* W16  = p;  p += WSZ;
    _Float16* q16  = p;  p += QSZ;
    _Float16* k16  = p;  p += QSZ;
    _Float16* vT16 = p;  p += QSZ;
    _Float16* oh16 = p;  p += QSZ;

    prep<<<2432, 256, 0, stream>>>(Xq, Xs, Wq, Wk, Wv, Xq16, Xs16, W16);
    qkv_mfma<<<dim3(64, 4, 3), 256, 0, stream>>>(Xq16, Xs16, W16, Wqb, Wkb, Wvb,
                                                 sc, q16, k16, vT16);
    lorentz_attn_v3<<<dim3(32, 8, 2), 256, 0, stream>>>(q16, k16, vT16, oh16);
    finalize_f16<<<(BB * NN) / 4, 256, 0, stream>>>(oh16, out);
}